// Round 10
// baseline (316.010 us; speedup 1.0000x reference)
//
#include <hip/hip_runtime.h>
#include <hip/hip_bf16.h>
#include <math.h>

#define B_ 8
#define S_ 512
#define E_ 768
#define H_ 12
#define HE_ (H_ * E_)
#define KSPLIT 8
#define KCHUNK (HE_ / KSPLIT)  // 1152 = 18*64

typedef __attribute__((ext_vector_type(4))) short bf16x4;
typedef __attribute__((ext_vector_type(8))) short bf16x8;
typedef __attribute__((ext_vector_type(16))) float f32x16;

__device__ inline void gload_lds16(const void* g, void* l) {
  __builtin_amdgcn_global_load_lds(
      (const __attribute__((address_space(1))) unsigned int*)g,
      (__attribute__((address_space(3))) unsigned int*)l, 16, 0, 0);
}

__device__ inline float bf2f(short u) {
  union { float f; unsigned int i; } c;
  c.i = ((unsigned int)(unsigned short)u) << 16;
  return c.f;
}
__device__ inline short f2bf(float f) {
  __hip_bfloat16 h = __float2bfloat16(f);
  return *reinterpret_cast<short*>(&h);
}

// ---------- f32 -> bf16 convert, float4/lane ----------
__global__ __launch_bounds__(256) void cvt_v(const float* __restrict__ in,
                                             short* __restrict__ out) {
  const long i = ((long)blockIdx.x * 256 + threadIdx.x) * 4;
  float4 v = *reinterpret_cast<const float4*>(in + i);
  bf16x4 o;
  o[0] = f2bf(v.x); o[1] = f2bf(v.y); o[2] = f2bf(v.z); o[3] = f2bf(v.w);
  *reinterpret_cast<bf16x4*>(out + i) = o;
}

// ---------- per-batch mask compaction ----------
__global__ __launch_bounds__(512) void mask_scan(const int* __restrict__ mask,
                                                 int* __restrict__ idx,
                                                 int* __restrict__ cntp) {
  const int b = blockIdx.x;
  const int t = threadIdx.x;
  const int wave = t >> 6, lane = t & 63;
  const bool keep = (mask[b * S_ + t] == 0);
  unsigned long long bal = __ballot(keep);
  const int wprefix = __popcll(bal & ((1ull << lane) - 1ull));
  __shared__ int wt[8];
  if (lane == 0) wt[wave] = __popcll(bal);
  idx[b * S_ + t] = 0;
  __syncthreads();
  int off = 0, total = 0;
#pragma unroll
  for (int i = 0; i < 8; ++i) {
    off += (i < wave) ? wt[i] : 0;
    total += wt[i];
  }
  if (keep) idx[b * S_ + off + wprefix] = t;
  if (t == 0) {
    cntp[2 * b] = total;
    int pad = (total + 63) & ~63;
    cntp[2 * b + 1] = pad > S_ ? S_ : pad;
  }
}

// ---------- vectorized transpose ----------
template <typename T, int VW>
__global__ __launch_bounds__(256) void transpose_v(const T* __restrict__ in, long inz,
                                                   short* __restrict__ out, long outz,
                                                   int R, int C) {
  __shared__ float t[64][65];
  in += (long)blockIdx.z * inz;
  out += (long)blockIdx.z * outz;
  const int bc = blockIdx.x * 64, br = blockIdx.y * 64;
  const int tid = threadIdx.x;
  constexpr int CPR = 64 / VW;
  constexpr int NP1 = 64 * CPR / 256;
#pragma unroll
  for (int ps = 0; ps < NP1; ++ps) {
    int q = tid + ps * 256;
    int r = q / CPR, c0 = (q % CPR) * VW;
    const T* src = in + (long)(br + r) * C + bc + c0;
    if constexpr (VW == 4) {
      float4 v = *reinterpret_cast<const float4*>(src);
      t[r][c0] = v.x; t[r][c0 + 1] = v.y; t[r][c0 + 2] = v.z; t[r][c0 + 3] = v.w;
    } else {
      bf16x8 v = *reinterpret_cast<const bf16x8*>(src);
#pragma unroll
      for (int j = 0; j < 8; ++j) t[r][c0 + j] = bf2f(v[j]);
    }
  }
  __syncthreads();
#pragma unroll
  for (int ps = 0; ps < 2; ++ps) {
    int q = tid + ps * 256;
    int e = q >> 3, s0 = (q & 7) * 8;
    bf16x8 o;
#pragma unroll
    for (int j = 0; j < 8; ++j) o[j] = f2bf(t[s0 + j][e]);
    *reinterpret_cast<bf16x8*>(out + (long)(bc + e) * R + br + s0) = o;
  }
}

// ---------- gather-transpose: pcT[z][e][j] = p[z][idx[b][j]][e] ----------
__global__ __launch_bounds__(256) void transpose_gather(const short* __restrict__ p,
                                                        const int* __restrict__ gidx,
                                                        const int* __restrict__ cntp,
                                                        short* __restrict__ out) {
  const int z = blockIdx.z, b = z / H_;
  const int br = blockIdx.y * 64;
  if (br >= cntp[2 * b + 1]) return;
  __shared__ float t[64][65];
  const short* in = p + (long)z * S_ * E_;
  short* o = out + (long)z * S_ * E_;
  const int bc = blockIdx.x * 64;
  const int tid = threadIdx.x;
#pragma unroll
  for (int ps = 0; ps < 2; ++ps) {
    int q = tid + ps * 256;
    int r = q >> 3, c0 = (q & 7) * 8;
    int srow = gidx[b * S_ + br + r];
    bf16x8 v = *reinterpret_cast<const bf16x8*>(in + (long)srow * E_ + bc + c0);
#pragma unroll
    for (int j = 0; j < 8; ++j) t[r][c0 + j] = bf2f(v[j]);
  }
  __syncthreads();
#pragma unroll
  for (int ps = 0; ps < 2; ++ps) {
    int q = tid + ps * 256;
    int e = q >> 3, s0 = (q & 7) * 8;
    bf16x8 o8;
#pragma unroll
    for (int j = 0; j < 8; ++j) o8[j] = f2bf(t[s0 + j][e]);
    *reinterpret_cast<bf16x8*>(o + (long)(bc + e) * S_ + br + s0) = o8;
  }
}

// ---------- MFMA GEMM (32x32x16) with T3-minimum double-buffer ----------
// Stage(t+1) issued BEFORE compute(t); ONE raw s_barrier + explicit vmcnt(0)
// per K-step (never __syncthreads - it would drain vmcnt before compute).
// T1 XCD swizzle + chunk-XOR LDS swizzle carried over (verified r5-r9).
template <bool OUT_BF16, bool ADD_BIAS, bool GATHER_B, bool K_FROM_CNT>
__global__ __launch_bounds__(256) void gemm_bt(
    const __hip_bfloat16* __restrict__ A, long As1, long As2, int lda,
    const __hip_bfloat16* __restrict__ BT, long Bs1, long Bs2, int ldb,
    void* __restrict__ Cv, long Cs1, long Cs2, int ldc,
    const float* __restrict__ bias, long biasS2, int zmod, int K, float scale,
    int nx, int ny, const int* __restrict__ gidx, const int* __restrict__ cntp) {
  constexpr int BM = 128, BN = 128, BK = 64;
  __shared__ __align__(16) __hip_bfloat16 sA[2][BM * BK];
  __shared__ __align__(16) __hip_bfloat16 sB[2][BN * BK];
  const int nwg = gridDim.x;
  const int cpx = nwg >> 3;
  const int id = blockIdx.x;
  const int w = (id & 7) * cpx + (id >> 3);
  const int bz = w / (nx * ny);
  const int rem = w - bz * nx * ny;
  const int by = rem / nx;
  const int bx = rem - by * nx;

  const int tid = threadIdx.x;
  const int wave = tid >> 6, lane = tid & 63;
  const int r32 = lane & 31, g2 = lane >> 5;
  const int zb = bz / zmod, zh = bz % zmod;
  const int bm = by * BM, bn = bx * BN;
  if (GATHER_B && bn >= cntp[2 * zb + 1]) return;  // uniform block exit
  int Keff = K;
  if (K_FROM_CNT) Keff = cntp[2 * zb + 1];
  A += (long)zb * As1 + (long)zh * As2;
  BT += (long)zb * Bs1 + (long)zh * Bs2;
  const int wm = (wave >> 1) * 64, wn = (wave & 1) * 64;
  const int swz = (r32 & 7) << 3;
  f32x16 acc[2][2] = {};
  const int e0 = tid * 8;

  int colp[4], rowp[4], growB[4];
#pragma unroll
  for (int p = 0; p < 4; ++p) {
    int ee = p * 2048 + e0;
    int row = ee >> 6;
    rowp[p] = row;
    colp[p] = (ee & 63) ^ ((row & 7) << 3);
    growB[p] = GATHER_B ? gidx[zb * S_ + bn + row] : (bn + row);
  }

  auto stage = [&](int t, int buf) {
    const int k0 = t * BK;
#pragma unroll
    for (int p = 0; p < 4; ++p) {
      int ee = p * 2048 + e0;
      gload_lds16(A + (long)(bm + rowp[p]) * lda + (k0 + colp[p]),
                  (char*)(sA[buf]) + ee * 2);
      gload_lds16(BT + (long)growB[p] * ldb + (k0 + colp[p]),
                  (char*)(sB[buf]) + ee * 2);
    }
  };

  const int NT = Keff / BK;
  stage(0, 0);
  asm volatile("s_waitcnt vmcnt(0)" ::: "memory");
  __builtin_amdgcn_sched_barrier(0);
  __builtin_amdgcn_s_barrier();

  int cur = 0;
  for (int t = 0; t < NT; ++t) {
    if (t + 1 < NT) stage(t + 1, cur ^ 1);  // prefetch overlaps compute below
    const __hip_bfloat16* pA = sA[cur];
    const __hip_bfloat16* pB = sB[cur];
#pragma unroll
    for (int ks = 0; ks < 4; ++ks) {
      bf16x8 aw[2], bw[2];
#pragma unroll
      for (int ti = 0; ti < 2; ++ti) {
        int row = wm + ti * 32 + r32;
        int c = (ks * 16 + g2 * 8) ^ swz;
        aw[ti] = *(const bf16x8*)(const void*)(pA + row * BK + c);
      }
#pragma unroll
      for (int tj = 0; tj < 2; ++tj) {
        int row = wn + tj * 32 + r32;
        int c = (ks * 16 + g2 * 8) ^ swz;
        bw[tj] = *(const bf16x8*)(const void*)(pB + row * BK + c);
      }
#pragma unroll
      for (int ti = 0; ti < 2; ++ti)
#pragma unroll
        for (int tj = 0; tj < 2; ++tj)
          acc[ti][tj] =
              __builtin_amdgcn_mfma_f32_32x32x16_bf16(aw[ti], bw[tj], acc[ti][tj], 0, 0, 0);
    }
    if (t + 1 < NT) {
      asm volatile("s_waitcnt vmcnt(0)" ::: "memory");  // stage(t+1) landed
      __builtin_amdgcn_sched_barrier(0);
      __builtin_amdgcn_s_barrier();  // + all waves consumed buf[cur]
      cur ^= 1;
    }
  }

  float* Cf = (float*)Cv;
  __hip_bfloat16* Cb = (__hip_bfloat16*)Cv;
  const long cbase = (long)zb * Cs1 + (long)zh * Cs2;
#pragma unroll
  for (int ti = 0; ti < 2; ++ti)
#pragma unroll
    for (int tj = 0; tj < 2; ++tj) {
      const int colv = bn + wn + tj * 32 + r32;
      const float bv = ADD_BIAS ? bias[(long)zh * biasS2 + colv] : 0.0f;
#pragma unroll
      for (int r = 0; r < 16; ++r) {
        int rowv = bm + wm + ti * 32 + (r & 3) + 8 * (r >> 2) + 4 * g2;
        float v = acc[ti][tj][r] * scale + bv;
        long off = cbase + (long)rowv * ldc + colv;
        if (OUT_BF16)
          Cb[off] = __float2bfloat16(v);
        else
          Cf[off] = v;
      }
    }
}

// ---------- softmax over compacted row, wave-per-row, IN-PLACE ----------
__global__ __launch_bounds__(256) void softmax_v(__hip_bfloat16* __restrict__ scores,
                                                 const int* __restrict__ cntp) {
  const int wave = threadIdx.x >> 6, lane = threadIdx.x & 63;
  const long row = (long)blockIdx.x * 4 + wave;
  const int b = (int)(row / ((long)H_ * S_));
  const int cnt = cntp[2 * b];
  short* sp = (short*)scores + row * S_ + lane * 8;
  bf16x8 sv = *reinterpret_cast<const bf16x8*>(sp);
  const int j0 = lane * 8;
  float v[8];
#pragma unroll
  for (int j = 0; j < 8; ++j) v[j] = (j0 + j < cnt) ? bf2f(sv[j]) : -INFINITY;
  float mx = v[0];
#pragma unroll
  for (int j = 1; j < 8; ++j) mx = fmaxf(mx, v[j]);
#pragma unroll
  for (int o = 32; o; o >>= 1) mx = fmaxf(mx, __shfl_xor(mx, o));
  float e[8], s = 0.0f;
#pragma unroll
  for (int j = 0; j < 8; ++j) {
    e[j] = expf(v[j] - mx);
    s += e[j];
  }
#pragma unroll
  for (int o = 32; o; o >>= 1) s += __shfl_xor(s, o);
  const float inv = 1.0f / s;
  bf16x8 o8;
#pragma unroll
  for (int j = 0; j < 8; ++j) o8[j] = f2bf(e[j] * inv);
  *reinterpret_cast<bf16x8*>(sp) = o8;
}

// ---------- reduce KSPLIT bf16 partials + bias + LayerNorm ----------
__global__ __launch_bounds__(192) void ln_v(const __hip_bfloat16* __restrict__ yp,
                                            const float* __restrict__ bo,
                                            const float* __restrict__ gamma,
                                            const float* __restrict__ beta,
                                            float* __restrict__ out) {
  const long nY = (long)B_ * S_ * E_;
  const long base = (long)blockIdx.x * E_;
  const int t = threadIdx.x;
  const int c0 = t * 4;
  float a[4];
  {
    float4 bv = *reinterpret_cast<const float4*>(bo + c0);
    a[0] = bv.x; a[1] = bv.y; a[2] = bv.z; a[3] = bv.w;
  }
#pragma unroll
  for (int k = 0; k < KSPLIT; ++k) {
    bf16x4 v = *reinterpret_cast<const bf16x4*>((const short*)yp + k * nY + base + c0);
#pragma unroll
    for (int j = 0; j < 4; ++j) a[j] += bf2f(v[j]);
  }
  float s = a[0] + a[1] + a[2] + a[3];
  float ss = a[0] * a[0] + a[1] * a[1] + a[2] * a[2] + a[3] * a[3];
#pragma unroll
  for (int o = 32; o; o >>= 1) {
    s += __shfl_xor(s, o);
    ss += __shfl_xor(ss, o);
  }
  __shared__ float r1[3], r2[3];
  const int wave = t >> 6, lane = t & 63;
  if (lane == 0) { r1[wave] = s; r2[wave] = ss; }
  __syncthreads();
  s = r1[0] + r1[1] + r1[2];
  ss = r2[0] + r2[1] + r2[2];
  const float mu = s * (1.0f / E_);
  const float var = ss * (1.0f / E_) - mu * mu;
  const float rstd = rsqrtf(var + 1e-5f);
  float4 g = *reinterpret_cast<const float4*>(gamma + c0);
  float4 bt = *reinterpret_cast<const float4*>(beta + c0);
  float4 o4;
  o4.x = (a[0] - mu) * rstd * g.x + bt.x;
  o4.y = (a[1] - mu) * rstd * g.y + bt.y;
  o4.z = (a[2] - mu) * rstd * g.z + bt.z;
  o4.w = (a[3] - mu) * rstd * g.w + bt.w;
  *reinterpret_cast<float4*>(out + base + c0) = o4;
}

extern "C" void kernel_launch(void* const* d_in, const int* in_sizes, int n_in,
                              void* d_out, int out_size, void* d_ws, size_t ws_size,
                              hipStream_t stream) {
  const float* x = (const float*)d_in[0];
  const int* mask = (const int*)d_in[1];
  const float* Wh = (const float*)d_in[2];
  const float* bh = (const float*)d_in[3];
  const float* Wo = (const float*)d_in[4];
  const float* bo = (const float*)d_in[5];
  const float* gamma = (const float*)d_in[6];
  const float* beta = (const float*)d_in[7];
  float* out = (float*)d_out;

  // ---- workspace: phase-aliased regions (~215.6 MB) ----
  const size_t nX = (size_t)B_ * S_ * E_;
  const size_t nWh = (size_t)H_ * E_ * E_;
  const size_t nP = (size_t)B_ * H_ * S_ * E_;
  const size_t nSc = (size_t)B_ * H_ * S_ * S_;
  char* base = (char*)d_ws;
  __hip_bfloat16* p = (__hip_bfloat16*)base;  // R_A: p, later cat
  __hip_bfloat16* cat = p;
  char* RB = base + nP * 2;
  __hip_bfloat16* pcT = (__hip_bfloat16*)RB;  // R_B: compacted p^T, later ypart (8x6.3MB)
  __hip_bfloat16* ypart = (__hip_bfloat16*)RB;
  char* RC = RB + nP * 2;
  __hip_bfloat16* xb = (__hip_bfloat16*)RC;   // R_C: xb+WhT, later scores/attn
  __hip_bfloat16* WhT = (__hip_bfloat16*)(RC + nX * 2);
  __hip_bfloat16* scores = (__hip_bfloat16*)RC;
  char* RD = RC + nSc * 2;
  __hip_bfloat16* WoT = (__hip_bfloat16*)RD;  // R_D: WoT
  int* idx = (int*)(RD + nWh * 2);
  int* cntp = idx + B_ * S_;

  dim3 t256(256);
  const float inv_sqrtE = 1.0f / sqrtf((float)E_);

  // 0. mask compaction
  mask_scan<<<dim3(B_), dim3(512), 0, stream>>>(mask, idx, cntp);
  // 1. x -> bf16
  cvt_v<<<dim3(nX / 1024), t256, 0, stream>>>(x, (short*)xb);
  // 2. WhT[h][o][e] = Wh[h][e][o]
  transpose_v<float, 4><<<dim3(12, 12, 12), t256, 0, stream>>>(
      Wh, (long)E_ * E_, (short*)WhT, (long)E_ * E_, E_, E_);
  // 3. WoT[o][k] = Wo[k][o]
  transpose_v<float, 4><<<dim3(12, 144, 1), t256, 0, stream>>>(
      Wo, 0, (short*)WoT, 0, HE_, E_);
  // 4. p = x·Wh + bh   (grid 6x4x96 = 2304)
  gemm_bt<true, true, false, false><<<dim3(6 * 4 * 96), t256, 0, stream>>>(
      xb, (long)S_ * E_, 0, E_, WhT, 0, (long)E_ * E_, E_, p, (long)H_ * S_ * E_,
      (long)S_ * E_, E_, bh, E_, H_, E_, 1.0f, 6, 4, nullptr, nullptr);
  // 5. scores[:, j] = p · p[idx[j],:]^T / sqrt(E)   (gathered-B, early-exit tiles)
  gemm_bt<true, false, true, false><<<dim3(4 * 4 * 96), t256, 0, stream>>>(
      p, (long)H_ * S_ * E_, (long)S_ * E_, E_, p, (long)H_ * S_ * E_, (long)S_ * E_, E_,
      scores, (long)H_ * S_ * S_, (long)S_ * S_, S_, nullptr, 0, H_, E_, inv_sqrtE, 4, 4,
      idx, cntp);
  // 6. softmax over compacted width cnt[b], in-place
  softmax_v<<<dim3(12288), t256, 0, stream>>>(scores, cntp);
  // 7. pcT[b,h,e,j] = p[b,h,idx[j],e]
  transpose_gather<<<dim3(12, 8, 96), t256, 0, stream>>>((const short*)p, idx, cntp,
                                                         (short*)pcT);
  // 8. o = attn_c · pc -> cat   (K bound = cnt_pad[b])
  gemm_bt<true, false, false, true><<<dim3(6 * 4 * 96), t256, 0, stream>>>(
      scores, (long)H_ * S_ * S_, (long)S_ * S_, S_, pcT, (long)H_ * E_ * S_,
      (long)E_ * S_, S_, cat, (long)S_ * HE_, (long)E_, HE_, nullptr, 0, H_, S_, 1.0f,
      6, 4, nullptr, cntp);
  // 9. split-K GEMM4 (grid 6x32x8 = 1536 = exactly 3 rounds at 2 blocks/CU)
  gemm_bt<true, false, false, false><<<dim3(6 * 32 * KSPLIT), t256, 0, stream>>>(
      cat, 0, KCHUNK, HE_, WoT, 0, KCHUNK, HE_, ypart, 0, (long)B_ * S_ * E_, E_,
      nullptr, 0, KSPLIT, KCHUNK, 1.0f, 6, 32, nullptr, nullptr);
  // 10. reduce partials + bias + LayerNorm
  ln_v<<<dim3(B_ * S_), dim3(192), 0, stream>>>(ypart, bo, gamma, beta, out);
}

// Round 11
// 306.862 us; speedup vs baseline: 1.0298x; 1.0298x over previous
//
#include <hip/hip_runtime.h>
#include <hip/hip_bf16.h>
#include <math.h>

#define B_ 8
#define S_ 512
#define E_ 768
#define H_ 12
#define HE_ (H_ * E_)
#define KSPLIT 6
#define KCHUNK (HE_ / KSPLIT)  // 1536

typedef __attribute__((ext_vector_type(4))) short bf16x4;
typedef __attribute__((ext_vector_type(8))) short bf16x8;
typedef __attribute__((ext_vector_type(16))) float f32x16;

__device__ inline void gload_lds16(const void* g, void* l) {
  __builtin_amdgcn_global_load_lds(
      (const __attribute__((address_space(1))) unsigned int*)g,
      (__attribute__((address_space(3))) unsigned int*)l, 16, 0, 0);
}

__device__ inline float bf2f(short u) {
  union { float f; unsigned int i; } c;
  c.i = ((unsigned int)(unsigned short)u) << 16;
  return c.f;
}
__device__ inline short f2bf(float f) {
  __hip_bfloat16 h = __float2bfloat16(f);
  return *reinterpret_cast<short*>(&h);
}

// ---------- f32 -> bf16 convert, float4/lane ----------
__global__ __launch_bounds__(256) void cvt_v(const float* __restrict__ in,
                                             short* __restrict__ out) {
  const long i = ((long)blockIdx.x * 256 + threadIdx.x) * 4;
  float4 v = *reinterpret_cast<const float4*>(in + i);
  bf16x4 o;
  o[0] = f2bf(v.x); o[1] = f2bf(v.y); o[2] = f2bf(v.z); o[3] = f2bf(v.w);
  *reinterpret_cast<bf16x4*>(out + i) = o;
}

// ---------- per-batch mask compaction ----------
__global__ __launch_bounds__(512) void mask_scan(const int* __restrict__ mask,
                                                 int* __restrict__ idx,
                                                 int* __restrict__ cntp) {
  const int b = blockIdx.x;
  const int t = threadIdx.x;
  const int wave = t >> 6, lane = t & 63;
  const bool keep = (mask[b * S_ + t] == 0);
  unsigned long long bal = __ballot(keep);
  const int wprefix = __popcll(bal & ((1ull << lane) - 1ull));
  __shared__ int wt[8];
  if (lane == 0) wt[wave] = __popcll(bal);
  idx[b * S_ + t] = 0;
  __syncthreads();
  int off = 0, total = 0;
#pragma unroll
  for (int i = 0; i < 8; ++i) {
    off += (i < wave) ? wt[i] : 0;
    total += wt[i];
  }
  if (keep) idx[b * S_ + off + wprefix] = t;
  if (t == 0) {
    cntp[2 * b] = total;
    int pad = (total + 63) & ~63;
    cntp[2 * b + 1] = pad > S_ ? S_ : pad;
  }
}

// ---------- vectorized transpose ----------
template <typename T, int VW>
__global__ __launch_bounds__(256) void transpose_v(const T* __restrict__ in, long inz,
                                                   short* __restrict__ out, long outz,
                                                   int R, int C) {
  __shared__ float t[64][65];
  in += (long)blockIdx.z * inz;
  out += (long)blockIdx.z * outz;
  const int bc = blockIdx.x * 64, br = blockIdx.y * 64;
  const int tid = threadIdx.x;
  constexpr int CPR = 64 / VW;
  constexpr int NP1 = 64 * CPR / 256;
#pragma unroll
  for (int ps = 0; ps < NP1; ++ps) {
    int q = tid + ps * 256;
    int r = q / CPR, c0 = (q % CPR) * VW;
    const T* src = in + (long)(br + r) * C + bc + c0;
    if constexpr (VW == 4) {
      float4 v = *reinterpret_cast<const float4*>(src);
      t[r][c0] = v.x; t[r][c0 + 1] = v.y; t[r][c0 + 2] = v.z; t[r][c0 + 3] = v.w;
    } else {
      bf16x8 v = *reinterpret_cast<const bf16x8*>(src);
#pragma unroll
      for (int j = 0; j < 8; ++j) t[r][c0 + j] = bf2f(v[j]);
    }
  }
  __syncthreads();
#pragma unroll
  for (int ps = 0; ps < 2; ++ps) {
    int q = tid + ps * 256;
    int e = q >> 3, s0 = (q & 7) * 8;
    bf16x8 o;
#pragma unroll
    for (int j = 0; j < 8; ++j) o[j] = f2bf(t[s0 + j][e]);
    *reinterpret_cast<bf16x8*>(out + (long)(bc + e) * R + br + s0) = o;
  }
}

// ---------- gather-transpose: pcT[z][e][j] = p[z][idx[b][j]][e] ----------
__global__ __launch_bounds__(256) void transpose_gather(const short* __restrict__ p,
                                                        const int* __restrict__ gidx,
                                                        const int* __restrict__ cntp,
                                                        short* __restrict__ out) {
  const int z = blockIdx.z, b = z / H_;
  const int br = blockIdx.y * 64;
  if (br >= cntp[2 * b + 1]) return;
  __shared__ float t[64][65];
  const short* in = p + (long)z * S_ * E_;
  short* o = out + (long)z * S_ * E_;
  const int bc = blockIdx.x * 64;
  const int tid = threadIdx.x;
#pragma unroll
  for (int ps = 0; ps < 2; ++ps) {
    int q = tid + ps * 256;
    int r = q >> 3, c0 = (q & 7) * 8;
    int srow = gidx[b * S_ + br + r];
    bf16x8 v = *reinterpret_cast<const bf16x8*>(in + (long)srow * E_ + bc + c0);
#pragma unroll
    for (int j = 0; j < 8; ++j) t[r][c0 + j] = bf2f(v[j]);
  }
  __syncthreads();
#pragma unroll
  for (int ps = 0; ps < 2; ++ps) {
    int q = tid + ps * 256;
    int e = q >> 3, s0 = (q & 7) * 8;
    bf16x8 o8;
#pragma unroll
    for (int j = 0; j < 8; ++j) o8[j] = f2bf(t[s0 + j][e]);
    *reinterpret_cast<bf16x8*>(o + (long)(bc + e) * S_ + br + s0) = o8;
  }
}

// ---------- MFMA GEMM (32x32x16), BM templated (128 -> 4 waves, 256 -> 8 waves) ----------
// Single-buffer 2-phase (r9 verified; dbuf regressed r10). T1 XCD swizzle +
// chunk-XOR LDS swizzle. BM=256 raises residency to 3 blocks x 8 waves = 24 waves/CU.
template <int BM, bool OUT_BF16, bool ADD_BIAS, bool GATHER_B, bool K_FROM_CNT>
__global__ __launch_bounds__(BM * 2) void gemm_bt(
    const __hip_bfloat16* __restrict__ A, long As1, long As2, int lda,
    const __hip_bfloat16* __restrict__ BT, long Bs1, long Bs2, int ldb,
    void* __restrict__ Cv, long Cs1, long Cs2, int ldc,
    const float* __restrict__ bias, long biasS2, int zmod, int K, float scale,
    int nx, int ny, const int* __restrict__ gidx, const int* __restrict__ cntp) {
  constexpr int BN = 128, BK = 64;
  constexpr int NTH = BM * 2;                 // threads: 256 or 512
  constexpr int BP = (BN * BK) / (NTH * 8);   // B staging passes: 4 or 2
  __shared__ __align__(16) __hip_bfloat16 sA[BM * BK];
  __shared__ __align__(16) __hip_bfloat16 sB[BN * BK];
  const int nwg = gridDim.x;
  const int cpx = nwg >> 3;
  const int id = blockIdx.x;
  const int w = (id & 7) * cpx + (id >> 3);
  const int bz = w / (nx * ny);
  const int rem = w - bz * nx * ny;
  const int by = rem / nx;
  const int bx = rem - by * nx;

  const int tid = threadIdx.x;
  const int wave = tid >> 6, lane = tid & 63;
  const int r32 = lane & 31, g2 = lane >> 5;
  const int zb = bz / zmod, zh = bz % zmod;
  const int bm = by * BM, bn = bx * BN;
  if (GATHER_B && bn >= cntp[2 * zb + 1]) return;
  int Keff = K;
  if (K_FROM_CNT) Keff = cntp[2 * zb + 1];
  A += (long)zb * As1 + (long)zh * As2;
  BT += (long)zb * Bs1 + (long)zh * Bs2;
  const int wm = (wave >> 1) * 64, wn = (wave & 1) * 64;
  const int swz = (r32 & 7) << 3;
  f32x16 acc[2][2] = {};
  const int e0 = tid * 8;

  int rowA[4], colA[4];
#pragma unroll
  for (int p = 0; p < 4; ++p) {
    int ee = p * NTH * 8 + e0;
    int row = ee >> 6;
    rowA[p] = row;
    colA[p] = (ee & 63) ^ ((row & 7) << 3);
  }
  int rowB[BP], colB[BP], growB[BP];
#pragma unroll
  for (int p = 0; p < BP; ++p) {
    int ee = p * NTH * 8 + e0;
    int row = ee >> 6;
    rowB[p] = row;
    colB[p] = (ee & 63) ^ ((row & 7) << 3);
    growB[p] = GATHER_B ? gidx[zb * S_ + bn + row] : (bn + row);
  }

  for (int k0 = 0; k0 < Keff; k0 += BK) {
#pragma unroll
    for (int p = 0; p < 4; ++p) {
      int ee = p * NTH * 8 + e0;
      gload_lds16(A + (long)(bm + rowA[p]) * lda + (k0 + colA[p]), (char*)sA + ee * 2);
    }
#pragma unroll
    for (int p = 0; p < BP; ++p) {
      int ee = p * NTH * 8 + e0;
      gload_lds16(BT + (long)growB[p] * ldb + (k0 + colB[p]), (char*)sB + ee * 2);
    }
    __syncthreads();
#pragma unroll
    for (int ks = 0; ks < 4; ++ks) {
      bf16x8 aw[2], bw[2];
#pragma unroll
      for (int ti = 0; ti < 2; ++ti) {
        int row = wm + ti * 32 + r32;
        int c = (ks * 16 + g2 * 8) ^ swz;
        aw[ti] = *(const bf16x8*)(const void*)(sA + row * BK + c);
      }
#pragma unroll
      for (int tj = 0; tj < 2; ++tj) {
        int row = wn + tj * 32 + r32;
        int c = (ks * 16 + g2 * 8) ^ swz;
        bw[tj] = *(const bf16x8*)(const void*)(sB + row * BK + c);
      }
#pragma unroll
      for (int ti = 0; ti < 2; ++ti)
#pragma unroll
        for (int tj = 0; tj < 2; ++tj)
          acc[ti][tj] =
              __builtin_amdgcn_mfma_f32_32x32x16_bf16(aw[ti], bw[tj], acc[ti][tj], 0, 0, 0);
    }
    __syncthreads();
  }

  float* Cf = (float*)Cv;
  __hip_bfloat16* Cb = (__hip_bfloat16*)Cv;
  const long cbase = (long)zb * Cs1 + (long)zh * Cs2;
#pragma unroll
  for (int ti = 0; ti < 2; ++ti)
#pragma unroll
    for (int tj = 0; tj < 2; ++tj) {
      const int colv = bn + wn + tj * 32 + r32;
      const float bv = ADD_BIAS ? bias[(long)zh * biasS2 + colv] : 0.0f;
#pragma unroll
      for (int r = 0; r < 16; ++r) {
        int rowv = bm + wm + ti * 32 + (r & 3) + 8 * (r >> 2) + 4 * g2;
        float v = acc[ti][tj][r] * scale + bv;
        long off = cbase + (long)rowv * ldc + colv;
        if (OUT_BF16)
          Cb[off] = __float2bfloat16(v);
        else
          Cf[off] = v;
      }
    }
}

// ---------- softmax over compacted row, wave-per-row, IN-PLACE ----------
__global__ __launch_bounds__(256) void softmax_v(__hip_bfloat16* __restrict__ scores,
                                                 const int* __restrict__ cntp) {
  const int wave = threadIdx.x >> 6, lane = threadIdx.x & 63;
  const long row = (long)blockIdx.x * 4 + wave;
  const int b = (int)(row / ((long)H_ * S_));
  const int cnt = cntp[2 * b];
  short* sp = (short*)scores + row * S_ + lane * 8;
  bf16x8 sv = *reinterpret_cast<const bf16x8*>(sp);
  const int j0 = lane * 8;
  float v[8];
#pragma unroll
  for (int j = 0; j < 8; ++j) v[j] = (j0 + j < cnt) ? bf2f(sv[j]) : -INFINITY;
  float mx = v[0];
#pragma unroll
  for (int j = 1; j < 8; ++j) mx = fmaxf(mx, v[j]);
#pragma unroll
  for (int o = 32; o; o >>= 1) mx = fmaxf(mx, __shfl_xor(mx, o));
  float e[8], s = 0.0f;
#pragma unroll
  for (int j = 0; j < 8; ++j) {
    e[j] = expf(v[j] - mx);
    s += e[j];
  }
#pragma unroll
  for (int o = 32; o; o >>= 1) s += __shfl_xor(s, o);
  const float inv = 1.0f / s;
  bf16x8 o8;
#pragma unroll
  for (int j = 0; j < 8; ++j) o8[j] = f2bf(e[j] * inv);
  *reinterpret_cast<bf16x8*>(sp) = o8;
}

// ---------- reduce KSPLIT bf16 partials + bias + LayerNorm ----------
__global__ __launch_bounds__(192) void ln_v(const __hip_bfloat16* __restrict__ yp,
                                            const float* __restrict__ bo,
                                            const float* __restrict__ gamma,
                                            const float* __restrict__ beta,
                                            float* __restrict__ out) {
  const long nY = (long)B_ * S_ * E_;
  const long base = (long)blockIdx.x * E_;
  const int t = threadIdx.x;
  const int c0 = t * 4;
  float a[4];
  {
    float4 bv = *reinterpret_cast<const float4*>(bo + c0);
    a[0] = bv.x; a[1] = bv.y; a[2] = bv.z; a[3] = bv.w;
  }
#pragma unroll
  for (int k = 0; k < KSPLIT; ++k) {
    bf16x4 v = *reinterpret_cast<const bf16x4*>((const short*)yp + k * nY + base + c0);
#pragma unroll
    for (int j = 0; j < 4; ++j) a[j] += bf2f(v[j]);
  }
  float s = a[0] + a[1] + a[2] + a[3];
  float ss = a[0] * a[0] + a[1] * a[1] + a[2] * a[2] + a[3] * a[3];
#pragma unroll
  for (int o = 32; o; o >>= 1) {
    s += __shfl_xor(s, o);
    ss += __shfl_xor(ss, o);
  }
  __shared__ float r1[3], r2[3];
  const int wave = t >> 6, lane = t & 63;
  if (lane == 0) { r1[wave] = s; r2[wave] = ss; }
  __syncthreads();
  s = r1[0] + r1[1] + r1[2];
  ss = r2[0] + r2[1] + r2[2];
  const float mu = s * (1.0f / E_);
  const float var = ss * (1.0f / E_) - mu * mu;
  const float rstd = rsqrtf(var + 1e-5f);
  float4 g = *reinterpret_cast<const float4*>(gamma + c0);
  float4 bt = *reinterpret_cast<const float4*>(beta + c0);
  float4 o4;
  o4.x = (a[0] - mu) * rstd * g.x + bt.x;
  o4.y = (a[1] - mu) * rstd * g.y + bt.y;
  o4.z = (a[2] - mu) * rstd * g.z + bt.z;
  o4.w = (a[3] - mu) * rstd * g.w + bt.w;
  *reinterpret_cast<float4*>(out + base + c0) = o4;
}

extern "C" void kernel_launch(void* const* d_in, const int* in_sizes, int n_in,
                              void* d_out, int out_size, void* d_ws, size_t ws_size,
                              hipStream_t stream) {
  const float* x = (const float*)d_in[0];
  const int* mask = (const int*)d_in[1];
  const float* Wh = (const float*)d_in[2];
  const float* bh = (const float*)d_in[3];
  const float* Wo = (const float*)d_in[4];
  const float* bo = (const float*)d_in[5];
  const float* gamma = (const float*)d_in[6];
  const float* beta = (const float*)d_in[7];
  float* out = (float*)d_out;

  // ---- workspace: phase-aliased regions (~215.6 MB) ----
  const size_t nX = (size_t)B_ * S_ * E_;
  const size_t nWh = (size_t)H_ * E_ * E_;
  const size_t nP = (size_t)B_ * H_ * S_ * E_;
  const size_t nSc = (size_t)B_ * H_ * S_ * S_;
  char* base = (char*)d_ws;
  __hip_bfloat16* p = (__hip_bfloat16*)base;  // R_A: p, later cat
  __hip_bfloat16* cat = p;
  char* RB = base + nP * 2;
  __hip_bfloat16* pcT = (__hip_bfloat16*)RB;  // R_B: compacted p^T, later ypart
  __hip_bfloat16* ypart = (__hip_bfloat16*)RB;
  char* RC = RB + nP * 2;
  __hip_bfloat16* xb = (__hip_bfloat16*)RC;   // R_C: xb+WhT, later scores/attn
  __hip_bfloat16* WhT = (__hip_bfloat16*)(RC + nX * 2);
  __hip_bfloat16* scores = (__hip_bfloat16*)RC;
  char* RD = RC + nSc * 2;
  __hip_bfloat16* WoT = (__hip_bfloat16*)RD;  // R_D: WoT
  int* idx = (int*)(RD + nWh * 2);
  int* cntp = idx + B_ * S_;

  dim3 t256(256), t512(512);
  const float inv_sqrtE = 1.0f / sqrtf((float)E_);

  // 0. mask compaction
  mask_scan<<<dim3(B_), dim3(512), 0, stream>>>(mask, idx, cntp);
  // 1. x -> bf16
  cvt_v<<<dim3(nX / 1024), t256, 0, stream>>>(x, (short*)xb);
  // 2. WhT[h][o][e] = Wh[h][e][o]
  transpose_v<float, 4><<<dim3(12, 12, 12), t256, 0, stream>>>(
      Wh, (long)E_ * E_, (short*)WhT, (long)E_ * E_, E_, E_);
  // 3. WoT[o][k] = Wo[k][o]
  transpose_v<float, 4><<<dim3(12, 144, 1), t256, 0, stream>>>(
      Wo, 0, (short*)WoT, 0, HE_, E_);
  // 4. p = x·Wh + bh   (BM=256: grid 6x2x96 = 1152, 512 thr, 24 waves/CU)
  gemm_bt<256, true, true, false, false><<<dim3(6 * 2 * 96), t512, 0, stream>>>(
      xb, (long)S_ * E_, 0, E_, WhT, 0, (long)E_ * E_, E_, p, (long)H_ * S_ * E_,
      (long)S_ * E_, E_, bh, E_, H_, E_, 1.0f, 6, 2, nullptr, nullptr);
  // 5. scores = p · p[idx]^T / sqrt(E)   (BM=128, gathered-B, early-exit tiles)
  gemm_bt<128, true, false, true, false><<<dim3(4 * 4 * 96), t256, 0, stream>>>(
      p, (long)H_ * S_ * E_, (long)S_ * E_, E_, p, (long)H_ * S_ * E_, (long)S_ * E_, E_,
      scores, (long)H_ * S_ * S_, (long)S_ * S_, S_, nullptr, 0, H_, E_, inv_sqrtE, 4, 4,
      idx, cntp);
  // 6. softmax over compacted width cnt[b], in-place
  softmax_v<<<dim3(12288), t256, 0, stream>>>(scores, cntp);
  // 7. pcT[b,h,e,j] = p[b,h,idx[j],e]
  transpose_gather<<<dim3(12, 8, 96), t256, 0, stream>>>((const short*)p, idx, cntp,
                                                         (short*)pcT);
  // 8. o = attn_c · pc -> cat   (BM=128, K bound = cnt_pad[b])
  gemm_bt<128, true, false, false, true><<<dim3(6 * 4 * 96), t256, 0, stream>>>(
      scores, (long)H_ * S_ * S_, (long)S_ * S_, S_, pcT, (long)H_ * E_ * S_,
      (long)E_ * S_, S_, cat, (long)S_ * HE_, (long)E_, HE_, nullptr, 0, H_, S_, 1.0f,
      6, 4, nullptr, cntp);
  // 9. split-K GEMM4 (BM=256: grid 6x16x6 = 576, 512 thr)
  gemm_bt<256, true, false, false, false><<<dim3(6 * 16 * KSPLIT), t512, 0, stream>>>(
      cat, 0, KCHUNK, HE_, WoT, 0, KCHUNK, HE_, ypart, 0, (long)B_ * S_ * E_, E_,
      nullptr, 0, KSPLIT, KCHUNK, 1.0f, 6, 16, nullptr, nullptr);
  // 10. reduce partials + bias + LayerNorm
  ln_v<<<dim3(B_ * S_), dim3(192), 0, stream>>>(ypart, bo, gamma, beta, out);
}

// Round 12
// 278.523 us; speedup vs baseline: 1.1346x; 1.1017x over previous
//
#include <hip/hip_runtime.h>
#include <hip/hip_bf16.h>
#include <math.h>

#define B_ 8
#define S_ 512
#define E_ 768
#define H_ 12
#define HE_ (H_ * E_)
#define KSPLIT 6
#define KCHUNK (HE_ / KSPLIT)  // 1536

typedef __attribute__((ext_vector_type(4))) short bf16x4;
typedef __attribute__((ext_vector_type(8))) short bf16x8;
typedef __attribute__((ext_vector_type(16))) float f32x16;

__device__ inline void gload_lds16(const void* g, void* l) {
  __builtin_amdgcn_global_load_lds(
      (const __attribute__((address_space(1))) unsigned int*)g,
      (__attribute__((address_space(3))) unsigned int*)l, 16, 0, 0);
}

__device__ inline float bf2f(short u) {
  union { float f; unsigned int i; } c;
  c.i = ((unsigned int)(unsigned short)u) << 16;
  return c.f;
}
__device__ inline short f2bf(float f) {
  __hip_bfloat16 h = __float2bfloat16(f);
  return *reinterpret_cast<short*>(&h);
}

// ---------- f32 -> bf16 convert, float4/lane ----------
__global__ __launch_bounds__(256) void cvt_v(const float* __restrict__ in,
                                             short* __restrict__ out) {
  const long i = ((long)blockIdx.x * 256 + threadIdx.x) * 4;
  float4 v = *reinterpret_cast<const float4*>(in + i);
  bf16x4 o;
  o[0] = f2bf(v.x); o[1] = f2bf(v.y); o[2] = f2bf(v.z); o[3] = f2bf(v.w);
  *reinterpret_cast<bf16x4*>(out + i) = o;
}

// ---------- per-batch mask compaction: idx[b][j] = j-th unmasked position ----------
__global__ __launch_bounds__(512) void mask_scan(const int* __restrict__ mask,
                                                 int* __restrict__ idx,
                                                 int* __restrict__ cntp) {
  const int b = blockIdx.x;
  const int t = threadIdx.x;
  const int wave = t >> 6, lane = t & 63;
  const bool keep = (mask[b * S_ + t] == 0);
  unsigned long long bal = __ballot(keep);
  const int wprefix = __popcll(bal & ((1ull << lane) - 1ull));
  __shared__ int wt[8];
  if (lane == 0) wt[wave] = __popcll(bal);
  idx[b * S_ + t] = 0;
  __syncthreads();
  int off = 0, total = 0;
#pragma unroll
  for (int i = 0; i < 8; ++i) {
    off += (i < wave) ? wt[i] : 0;
    total += wt[i];
  }
  if (keep) idx[b * S_ + off + wprefix] = t;
  if (t == 0) {
    cntp[2 * b] = total;
    int pad = (total + 63) & ~63;
    cntp[2 * b + 1] = pad > S_ ? S_ : pad;
  }
}

// ---------- vectorized transpose ----------
template <typename T, int VW>
__global__ __launch_bounds__(256) void transpose_v(const T* __restrict__ in, long inz,
                                                   short* __restrict__ out, long outz,
                                                   int R, int C) {
  __shared__ float t[64][65];
  in += (long)blockIdx.z * inz;
  out += (long)blockIdx.z * outz;
  const int bc = blockIdx.x * 64, br = blockIdx.y * 64;
  const int tid = threadIdx.x;
  constexpr int CPR = 64 / VW;
  constexpr int NP1 = 64 * CPR / 256;
#pragma unroll
  for (int ps = 0; ps < NP1; ++ps) {
    int q = tid + ps * 256;
    int r = q / CPR, c0 = (q % CPR) * VW;
    const T* src = in + (long)(br + r) * C + bc + c0;
    if constexpr (VW == 4) {
      float4 v = *reinterpret_cast<const float4*>(src);
      t[r][c0] = v.x; t[r][c0 + 1] = v.y; t[r][c0 + 2] = v.z; t[r][c0 + 3] = v.w;
    } else {
      bf16x8 v = *reinterpret_cast<const bf16x8*>(src);
#pragma unroll
      for (int j = 0; j < 8; ++j) t[r][c0 + j] = bf2f(v[j]);
    }
  }
  __syncthreads();
#pragma unroll
  for (int ps = 0; ps < 2; ++ps) {
    int q = tid + ps * 256;
    int e = q >> 3, s0 = (q & 7) * 8;
    bf16x8 o;
#pragma unroll
    for (int j = 0; j < 8; ++j) o[j] = f2bf(t[s0 + j][e]);
    *reinterpret_cast<bf16x8*>(out + (long)(bc + e) * R + br + s0) = o;
  }
}

// ---------- gather-transpose: pcT[z][e][j] = p[z][idx[b][j]][e] ----------
__global__ __launch_bounds__(256) void transpose_gather(const short* __restrict__ p,
                                                        const int* __restrict__ gidx,
                                                        const int* __restrict__ cntp,
                                                        short* __restrict__ out) {
  const int z = blockIdx.z, b = z / H_;
  const int br = blockIdx.y * 64;
  if (br >= cntp[2 * b + 1]) return;
  __shared__ float t[64][65];
  const short* in = p + (long)z * S_ * E_;
  short* o = out + (long)z * S_ * E_;
  const int bc = blockIdx.x * 64;
  const int tid = threadIdx.x;
#pragma unroll
  for (int ps = 0; ps < 2; ++ps) {
    int q = tid + ps * 256;
    int r = q >> 3, c0 = (q & 7) * 8;
    int srow = gidx[b * S_ + br + r];
    bf16x8 v = *reinterpret_cast<const bf16x8*>(in + (long)srow * E_ + bc + c0);
#pragma unroll
    for (int j = 0; j < 8; ++j) t[r][c0 + j] = bf2f(v[j]);
  }
  __syncthreads();
#pragma unroll
  for (int ps = 0; ps < 2; ++ps) {
    int q = tid + ps * 256;
    int e = q >> 3, s0 = (q & 7) * 8;
    bf16x8 o8;
#pragma unroll
    for (int j = 0; j < 8; ++j) o8[j] = f2bf(t[s0 + j][e]);
    *reinterpret_cast<bf16x8*>(o + (long)(bc + e) * S_ + br + s0) = o8;
  }
}

// ---------- MFMA GEMM (32x32x16): C[M,N] = A[M,K] * (BT[N,K])^T ----------
// r9-verified local optimum: 128^2 tile, 4 waves, 32KB single-buffer LDS,
// T1 XCD swizzle + chunk-XOR LDS swizzle. GATHER_B: B rows via gidx +
// early-exit tiles. K_FROM_CNT: K bound = cnt_pad[b].
template <bool OUT_BF16, bool ADD_BIAS, bool GATHER_B, bool K_FROM_CNT>
__global__ __launch_bounds__(256) void gemm_bt(
    const __hip_bfloat16* __restrict__ A, long As1, long As2, int lda,
    const __hip_bfloat16* __restrict__ BT, long Bs1, long Bs2, int ldb,
    void* __restrict__ Cv, long Cs1, long Cs2, int ldc,
    const float* __restrict__ bias, long biasS2, int zmod, int K, float scale,
    int nx, int ny, const int* __restrict__ gidx, const int* __restrict__ cntp) {
  constexpr int BM = 128, BN = 128, BK = 64;
  __shared__ __align__(16) __hip_bfloat16 sA[BM * BK];
  __shared__ __align__(16) __hip_bfloat16 sB[BN * BK];
  const int nwg = gridDim.x;
  const int cpx = nwg >> 3;
  const int id = blockIdx.x;
  const int w = (id & 7) * cpx + (id >> 3);
  const int bz = w / (nx * ny);
  const int rem = w - bz * nx * ny;
  const int by = rem / nx;
  const int bx = rem - by * nx;

  const int tid = threadIdx.x;
  const int wave = tid >> 6, lane = tid & 63;
  const int r32 = lane & 31, g2 = lane >> 5;
  const int zb = bz / zmod, zh = bz % zmod;
  const int bm = by * BM, bn = bx * BN;
  if (GATHER_B && bn >= cntp[2 * zb + 1]) return;  // uniform exit, pre-barrier
  int Keff = K;
  if (K_FROM_CNT) Keff = cntp[2 * zb + 1];
  A += (long)zb * As1 + (long)zh * As2;
  BT += (long)zb * Bs1 + (long)zh * Bs2;
  const int wm = (wave >> 1) * 64, wn = (wave & 1) * 64;
  const int swz = (r32 & 7) << 3;
  f32x16 acc[2][2] = {};
  const int e0 = tid * 8;

  int colp[4], rowp[4], growB[4];
#pragma unroll
  for (int p = 0; p < 4; ++p) {
    int ee = p * 2048 + e0;
    int row = ee >> 6;
    rowp[p] = row;
    colp[p] = (ee & 63) ^ ((row & 7) << 3);
    growB[p] = GATHER_B ? gidx[zb * S_ + bn + row] : (bn + row);
  }

  for (int k0 = 0; k0 < Keff; k0 += BK) {
#pragma unroll
    for (int p = 0; p < 4; ++p) {
      int ee = p * 2048 + e0;
      gload_lds16(A + (long)(bm + rowp[p]) * lda + (k0 + colp[p]), (char*)sA + ee * 2);
      gload_lds16(BT + (long)growB[p] * ldb + (k0 + colp[p]), (char*)sB + ee * 2);
    }
    __syncthreads();
#pragma unroll
    for (int ks = 0; ks < 4; ++ks) {
      bf16x8 aw[2], bw[2];
#pragma unroll
      for (int ti = 0; ti < 2; ++ti) {
        int row = wm + ti * 32 + r32;
        int c = (ks * 16 + g2 * 8) ^ swz;
        aw[ti] = *(const bf16x8*)(const void*)(sA + row * BK + c);
      }
#pragma unroll
      for (int tj = 0; tj < 2; ++tj) {
        int row = wn + tj * 32 + r32;
        int c = (ks * 16 + g2 * 8) ^ swz;
        bw[tj] = *(const bf16x8*)(const void*)(sB + row * BK + c);
      }
#pragma unroll
      for (int ti = 0; ti < 2; ++ti)
#pragma unroll
        for (int tj = 0; tj < 2; ++tj)
          acc[ti][tj] =
              __builtin_amdgcn_mfma_f32_32x32x16_bf16(aw[ti], bw[tj], acc[ti][tj], 0, 0, 0);
    }
    __syncthreads();
  }

  float* Cf = (float*)Cv;
  __hip_bfloat16* Cb = (__hip_bfloat16*)Cv;
  const long cbase = (long)zb * Cs1 + (long)zh * Cs2;
#pragma unroll
  for (int ti = 0; ti < 2; ++ti)
#pragma unroll
    for (int tj = 0; tj < 2; ++tj) {
      const int colv = bn + wn + tj * 32 + r32;
      const float bv = ADD_BIAS ? bias[(long)zh * biasS2 + colv] : 0.0f;
#pragma unroll
      for (int r = 0; r < 16; ++r) {
        int rowv = bm + wm + ti * 32 + (r & 3) + 8 * (r >> 2) + 4 * g2;
        float v = acc[ti][tj][r] * scale + bv;
        long off = cbase + (long)rowv * ldc + colv;
        if (OUT_BF16)
          Cb[off] = __float2bfloat16(v);
        else
          Cf[off] = v;
      }
    }
}

// ---------- softmax over compacted row, wave-per-row, IN-PLACE ----------
__global__ __launch_bounds__(256) void softmax_v(__hip_bfloat16* __restrict__ scores,
                                                 const int* __restrict__ cntp) {
  const int wave = threadIdx.x >> 6, lane = threadIdx.x & 63;
  const long row = (long)blockIdx.x * 4 + wave;
  const int b = (int)(row / ((long)H_ * S_));
  const int cnt = cntp[2 * b];
  short* sp = (short*)scores + row * S_ + lane * 8;
  bf16x8 sv = *reinterpret_cast<const bf16x8*>(sp);
  const int j0 = lane * 8;
  float v[8];
#pragma unroll
  for (int j = 0; j < 8; ++j) v[j] = (j0 + j < cnt) ? bf2f(sv[j]) : -INFINITY;
  float mx = v[0];
#pragma unroll
  for (int j = 1; j < 8; ++j) mx = fmaxf(mx, v[j]);
#pragma unroll
  for (int o = 32; o; o >>= 1) mx = fmaxf(mx, __shfl_xor(mx, o));
  float e[8], s = 0.0f;
#pragma unroll
  for (int j = 0; j < 8; ++j) {
    e[j] = expf(v[j] - mx);
    s += e[j];
  }
#pragma unroll
  for (int o = 32; o; o >>= 1) s += __shfl_xor(s, o);
  const float inv = 1.0f / s;
  bf16x8 o8;
#pragma unroll
  for (int j = 0; j < 8; ++j) o8[j] = f2bf(e[j] * inv);
  *reinterpret_cast<bf16x8*>(sp) = o8;
}

// ---------- reduce KSPLIT bf16 partials + bias + LayerNorm ----------
__global__ __launch_bounds__(192) void ln_v(const __hip_bfloat16* __restrict__ yp,
                                            const float* __restrict__ bo,
                                            const float* __restrict__ gamma,
                                            const float* __restrict__ beta,
                                            float* __restrict__ out) {
  const long nY = (long)B_ * S_ * E_;
  const long base = (long)blockIdx.x * E_;
  const int t = threadIdx.x;
  const int c0 = t * 4;
  float a[4];
  {
    float4 bv = *reinterpret_cast<const float4*>(bo + c0);
    a[0] = bv.x; a[1] = bv.y; a[2] = bv.z; a[3] = bv.w;
  }
#pragma unroll
  for (int k = 0; k < KSPLIT; ++k) {
    bf16x4 v = *reinterpret_cast<const bf16x4*>((const short*)yp + k * nY + base + c0);
#pragma unroll
    for (int j = 0; j < 4; ++j) a[j] += bf2f(v[j]);
  }
  float s = a[0] + a[1] + a[2] + a[3];
  float ss = a[0] * a[0] + a[1] * a[1] + a[2] * a[2] + a[3] * a[3];
#pragma unroll
  for (int o = 32; o; o >>= 1) {
    s += __shfl_xor(s, o);
    ss += __shfl_xor(ss, o);
  }
  __shared__ float r1[3], r2[3];
  const int wave = t >> 6, lane = t & 63;
  if (lane == 0) { r1[wave] = s; r2[wave] = ss; }
  __syncthreads();
  s = r1[0] + r1[1] + r1[2];
  ss = r2[0] + r2[1] + r2[2];
  const float mu = s * (1.0f / E_);
  const float var = ss * (1.0f / E_) - mu * mu;
  const float rstd = rsqrtf(var + 1e-5f);
  float4 g = *reinterpret_cast<const float4*>(gamma + c0);
  float4 bt = *reinterpret_cast<const float4*>(beta + c0);
  float4 o4;
  o4.x = (a[0] - mu) * rstd * g.x + bt.x;
  o4.y = (a[1] - mu) * rstd * g.y + bt.y;
  o4.z = (a[2] - mu) * rstd * g.z + bt.z;
  o4.w = (a[3] - mu) * rstd * g.w + bt.w;
  *reinterpret_cast<float4*>(out + base + c0) = o4;
}

extern "C" void kernel_launch(void* const* d_in, const int* in_sizes, int n_in,
                              void* d_out, int out_size, void* d_ws, size_t ws_size,
                              hipStream_t stream) {
  const float* x = (const float*)d_in[0];
  const int* mask = (const int*)d_in[1];
  const float* Wh = (const float*)d_in[2];
  const float* bh = (const float*)d_in[3];
  const float* Wo = (const float*)d_in[4];
  const float* bo = (const float*)d_in[5];
  const float* gamma = (const float*)d_in[6];
  const float* beta = (const float*)d_in[7];
  float* out = (float*)d_out;

  // ---- workspace: phase-aliased regions (~215.6 MB) ----
  const size_t nX = (size_t)B_ * S_ * E_;
  const size_t nWh = (size_t)H_ * E_ * E_;
  const size_t nP = (size_t)B_ * H_ * S_ * E_;
  const size_t nSc = (size_t)B_ * H_ * S_ * S_;
  char* base = (char*)d_ws;
  __hip_bfloat16* p = (__hip_bfloat16*)base;  // R_A: p, later cat
  __hip_bfloat16* cat = p;
  char* RB = base + nP * 2;
  __hip_bfloat16* pcT = (__hip_bfloat16*)RB;  // R_B: compacted p^T, later ypart
  __hip_bfloat16* ypart = (__hip_bfloat16*)RB;
  char* RC = RB + nP * 2;
  __hip_bfloat16* xb = (__hip_bfloat16*)RC;   // R_C: xb+WhT, later scores/attn
  __hip_bfloat16* WhT = (__hip_bfloat16*)(RC + nX * 2);
  __hip_bfloat16* scores = (__hip_bfloat16*)RC;
  char* RD = RC + nSc * 2;
  __hip_bfloat16* WoT = (__hip_bfloat16*)RD;  // R_D: WoT
  int* idx = (int*)(RD + nWh * 2);
  int* cntp = idx + B_ * S_;

  dim3 t256(256);
  const float inv_sqrtE = 1.0f / sqrtf((float)E_);

  // 0. mask compaction
  mask_scan<<<dim3(B_), dim3(512), 0, stream>>>(mask, idx, cntp);
  // 1. x -> bf16
  cvt_v<<<dim3(nX / 1024), t256, 0, stream>>>(x, (short*)xb);
  // 2. WhT[h][o][e] = Wh[h][e][o]
  transpose_v<float, 4><<<dim3(12, 12, 12), t256, 0, stream>>>(
      Wh, (long)E_ * E_, (short*)WhT, (long)E_ * E_, E_, E_);
  // 3. WoT[o][k] = Wo[k][o]
  transpose_v<float, 4><<<dim3(12, 144, 1), t256, 0, stream>>>(
      Wo, 0, (short*)WoT, 0, HE_, E_);
  // 4. p = x·Wh + bh   (grid 6x4x96 = 2304)
  gemm_bt<true, true, false, false><<<dim3(6 * 4 * 96), t256, 0, stream>>>(
      xb, (long)S_ * E_, 0, E_, WhT, 0, (long)E_ * E_, E_, p, (long)H_ * S_ * E_,
      (long)S_ * E_, E_, bh, E_, H_, E_, 1.0f, 6, 4, nullptr, nullptr);
  // 5. scores = p · p[idx]^T / sqrt(E)   (gathered-B, early-exit tiles)
  gemm_bt<true, false, true, false><<<dim3(4 * 4 * 96), t256, 0, stream>>>(
      p, (long)H_ * S_ * E_, (long)S_ * E_, E_, p, (long)H_ * S_ * E_, (long)S_ * E_, E_,
      scores, (long)H_ * S_ * S_, (long)S_ * S_, S_, nullptr, 0, H_, E_, inv_sqrtE, 4, 4,
      idx, cntp);
  // 6. softmax over compacted width cnt[b], in-place
  softmax_v<<<dim3(12288), t256, 0, stream>>>(scores, cntp);
  // 7. pcT[b,h,e,j] = p[b,h,idx[j],e]
  transpose_gather<<<dim3(12, 8, 96), t256, 0, stream>>>((const short*)p, idx, cntp,
                                                         (short*)pcT);
  // 8. o = attn_c · pc -> cat   (K bound = cnt_pad[b])
  gemm_bt<true, false, false, true><<<dim3(6 * 4 * 96), t256, 0, stream>>>(
      scores, (long)H_ * S_ * S_, (long)S_ * S_, S_, pcT, (long)H_ * E_ * S_,
      (long)E_ * S_, S_, cat, (long)S_ * HE_, (long)E_, HE_, nullptr, 0, H_, S_, 1.0f,
      6, 4, nullptr, cntp);
  // 9. split-K GEMM4 (grid 6x32x6 = 1152, bf16 partials)
  gemm_bt<true, false, false, false><<<dim3(6 * 32 * KSPLIT), t256, 0, stream>>>(
      cat, 0, KCHUNK, HE_, WoT, 0, KCHUNK, HE_, ypart, 0, (long)B_ * S_ * E_, E_,
      nullptr, 0, KSPLIT, KCHUNK, 1.0f, 6, 32, nullptr, nullptr);
  // 10. reduce partials + bias + LayerNorm
  ln_v<<<dim3(B_ * S_), dim3(192), 0, stream>>>(ypart, bo, gamma, beta, out);
}